// Round 15
// baseline (133.583 us; speedup 1.0000x reference)
//
#include <hip/hip_runtime.h>
#include <math.h>

#define TOKS 16384
#define CDIM 128
#define NH 4
#define HD 32
#define HID 512
#define QSCALE 0.17677669529663687f
#define LEPS 1e-5f

typedef const float* fp;
typedef const unsigned short* bfp16;
typedef __attribute__((ext_vector_type(8))) short bf16x8;
typedef __attribute__((ext_vector_type(4))) float f32x4;

__device__ inline unsigned int bfp2(float a, float b) {
    unsigned int ua = __float_as_uint(a); ua = (ua + 0x7FFFu + ((ua >> 16) & 1u)) >> 16;
    unsigned int ub = __float_as_uint(b); ub = (ub + 0x7FFFu + ((ub >> 16) & 1u)) >> 16;
    return ua | (ub << 16);
}
__device__ inline unsigned short bf1(float a) {
    unsigned int u = __float_as_uint(a);
    return (unsigned short)((u + 0x7FFFu + ((u >> 16) & 1u)) >> 16);
}
__device__ inline float lo16(unsigned int u) { return __uint_as_float(u << 16); }
__device__ inline float hi16(unsigned int u) { return __uint_as_float(u & 0xFFFF0000u); }

// ---------------- prep: weight convert+transpose (768 blocks) ----------------
__global__ __launch_bounds__(256) void prep(fp qw, fp pw, fp f1w, fp f2w,
                                            unsigned short* __restrict__ wt) {
    int e = blockIdx.x * 256 + threadIdx.x;
    float v;
    if (e < 49152) { int n = e >> 7, k = e & 127; v = qw[(size_t)k * 384 + n]; }
    else if (e < 65536) {        // wt1f: proj W[128 out][128 k], 32 frags (rt*4+kk)
        int i = e - 49152;
        int frag = i >> 9, w = i & 511, lane = w >> 3, el = w & 7;
        int rt = frag >> 2, kk = frag & 3;
        int row = rt * 16 + (lane & 15);
        int k = kk * 32 + (lane >> 4) * 8 + el;
        v = pw[(size_t)k * 128 + row];
    } else if (e < 131072) {     // wt2f: fc1 W[512 hid][128 k], 128 frags (rt*4+kk)
        int i = e - 65536;
        int frag = i >> 9, w = i & 511, lane = w >> 3, el = w & 7;
        int rt = frag >> 2, kk = frag & 3;
        int row = rt * 16 + (lane & 15);
        int k = kk * 32 + (lane >> 4) * 8 + el;
        v = f1w[(size_t)k * 512 + row];
    } else {                     // wt3f: fc2 W[128 out][512 k], 128 frags (rt*16+kc)
        int i = e - 131072;
        int frag = i >> 9, w = i & 511, lane = w >> 3, el = w & 7;
        int rt = frag >> 4, kc = frag & 15;
        int row = rt * 16 + (lane & 15);
        int k = kc * 32 + (lane >> 4) * 8 + el;
        v = f2w[(size_t)k * 128 + row];
    }
    wt[e] = bf1(v);
}

// ---------------- k1: fused LN1(x) + QKV GEMM (K=128, N=384); Q->f32, K/V->bf16 ------
__global__ __launch_bounds__(256) void k1_mfma(fp x, fp g1, fp b1, bfp16 wt0, fp wb,
                                               float* __restrict__ qb,
                                               unsigned short* __restrict__ kvb) {
    __shared__ unsigned int lds[12288];
    const int m0 = blockIdx.x * 128;
    const int nb = blockIdx.y * 64;
    const int tid = threadIdx.x;
#pragma unroll
    for (int i = 0; i < 8; i++) {
        int slot = tid + i * 256;
        int m = slot >> 4, c16 = slot & 15;
        const float4 v0 = *(const float4*)(x + (size_t)(m0 + m) * CDIM + c16 * 8);
        const float4 v1 = *(const float4*)(x + (size_t)(m0 + m) * CDIM + c16 * 8 + 4);
        float s = v0.x + v0.y + v0.z + v0.w + v1.x + v1.y + v1.z + v1.w;
        float q = v0.x * v0.x + v0.y * v0.y + v0.z * v0.z + v0.w * v0.w
                + v1.x * v1.x + v1.y * v1.y + v1.z * v1.z + v1.w * v1.w;
#pragma unroll
        for (int mm = 8; mm >= 1; mm >>= 1) { s += __shfl_xor(s, mm); q += __shfl_xor(q, mm); }
        float mu = s * (1.f / 128.f);
        float rs = rsqrtf(q * (1.f / 128.f) - mu * mu + LEPS);
        const float4 ga = *(const float4*)(g1 + c16 * 8);
        const float4 gb = *(const float4*)(g1 + c16 * 8 + 4);
        const float4 ba = *(const float4*)(b1 + c16 * 8);
        const float4 bb = *(const float4*)(b1 + c16 * 8 + 4);
        uint4 o;
        o.x = bfp2((v0.x - mu) * rs * ga.x + ba.x, (v0.y - mu) * rs * ga.y + ba.y);
        o.y = bfp2((v0.z - mu) * rs * ga.z + ba.z, (v0.w - mu) * rs * ga.w + ba.w);
        o.z = bfp2((v1.x - mu) * rs * gb.x + bb.x, (v1.y - mu) * rs * gb.y + bb.y);
        o.w = bfp2((v1.z - mu) * rs * gb.z + bb.z, (v1.w - mu) * rs * gb.w + bb.w);
        *(uint4*)&lds[m * 64 + ((c16 ^ (m & 15)) << 2)] = o;
    }
#pragma unroll
    for (int i = 0; i < 4; i++) {
        int slot = tid + i * 256;
        int n = slot >> 4, c16 = slot & 15;
        const uint4 v4 = *(const uint4*)(wt0 + (size_t)(nb + n) * 128 + c16 * 8);
        *(uint4*)&lds[8192 + n * 64 + (c16 ^ (n & 15)) * 4] = v4;
    }
    __syncthreads();

    const int lane = tid & 63, wid = tid >> 6, quad = lane >> 4, l16 = lane & 15;
    f32x4 acc[2][4];
#pragma unroll
    for (int mt = 0; mt < 2; mt++)
#pragma unroll
        for (int nt = 0; nt < 4; nt++) acc[mt][nt] = (f32x4){0.f, 0.f, 0.f, 0.f};
#pragma unroll
    for (int kk = 0; kk < 4; kk++) {
        int c = kk * 4 + quad;
        bf16x8 a0 = *(bf16x8*)&lds[(wid * 32 + l16) * 64 + (c ^ l16) * 4];
        bf16x8 a1 = *(bf16x8*)&lds[(wid * 32 + 16 + l16) * 64 + (c ^ l16) * 4];
#pragma unroll
        for (int nt = 0; nt < 4; nt++) {
            bf16x8 bf = *(bf16x8*)&lds[8192 + (nt * 16 + l16) * 64 + (c ^ l16) * 4];
            acc[0][nt] = __builtin_amdgcn_mfma_f32_16x16x32_bf16(a0, bf, acc[0][nt], 0, 0, 0);
            acc[1][nt] = __builtin_amdgcn_mfma_f32_16x16x32_bf16(a1, bf, acc[1][nt], 0, 0, 0);
        }
    }
#pragma unroll
    for (int nt = 0; nt < 4; nt++) {
        int col = nb + nt * 16 + l16;
        float bias = wb[col];
#pragma unroll
        for (int mt = 0; mt < 2; mt++)
#pragma unroll
            for (int r = 0; r < 4; r++) {
                int row = m0 + wid * 32 + mt * 16 + quad * 4 + r;
                float vres = acc[mt][nt][r] + bias;
                if (col < 128)
                    qb[(size_t)row * 128 + col] = vres * QSCALE;
                else if (col < 256)
                    kvb[(size_t)row * 256 + (col - 128)] = bf1(vres);
                else
                    kvb[(size_t)row * 256 + 128 + (col - 256)] = bf1(vres);
            }
    }
}

// ---------------- k2: MFMA neighborhood attention, block = (tile, head) --------------
// 1024 blocks x 256 threads (4 waves). Dense 14x14 region (224 padded), swapped
// QK^T: S^T = mfma(K, Q^T) -> each lane holds ALL scores for one query (q = l16;
// regions split across quads+frags) -> mask/bias/softmax with 2 shfl_xor only.
// P (normalized, bf16) -> LDS rows [q][224]; V staged TRANSPOSED Vt[d][r];
// PV = mfma(P, Vt). LDS 61KB: K[224 rows,80B pad] | Vt[32,464B pad] | P[64,464B pad].
__global__ __launch_bounds__(256) void k2_attn(const float* __restrict__ qb,
                                               const unsigned short* __restrict__ kvb,
                                               fp rpb, unsigned short* __restrict__ attnb) {
    __shared__ unsigned int lds[15616];
    unsigned short* ldsu = (unsigned short*)lds;
    const int blk = blockIdx.x;              // 1024 = 256 tiles * 4 heads
    const int head = blk & 3;
    const int tile = blk >> 2;
    const int bb = tile >> 6;
    const int ty0 = ((tile >> 3) & 7) << 3;
    const int tx0 = (tile & 7) << 3;
    const int ry0 = min(max(ty0 - 3, 0), 50);
    const int rx0 = min(max(tx0 - 3, 0), 50);
    const int tid = threadIdx.x;
    const int base = bb << 12;

    // stage K [196][32]bf16 (rows padded to 80B) and Vt [32][r] (rows padded to 464B)
#pragma unroll
    for (int it = 0; it < 4; it++) {
        int slot = it * 256 + tid;
        if (slot < 784) {
            int r = slot >> 2, c = slot & 3;
            int i = (r * 9363) >> 17, j = r - i * 14;   // r/14, r%14
            size_t tok = (size_t)(base + (ry0 + i) * 64 + rx0 + j);
            const uint4 kk4 = *(const uint4*)(kvb + tok * 256 + head * 32 + c * 8);
            *(uint4*)&lds[r * 20 + c * 4] = kk4;
            const uint4 vv4 = *(const uint4*)(kvb + tok * 256 + 128 + head * 32 + c * 8);
            unsigned int vv[4] = {vv4.x, vv4.y, vv4.z, vv4.w};
#pragma unroll
            for (int e = 0; e < 4; e++) {
                int d0 = c * 8 + e * 2;
                ldsu[8960 + d0 * 232 + r] = (unsigned short)(vv[e] & 0xFFFFu);
                ldsu[8960 + (d0 + 1) * 232 + r] = (unsigned short)(vv[e] >> 16);
            }
        }
    }
    // zero Vt cols [196,224): 32 rows x 14 uints (NaN safety for PV over padding)
#pragma unroll
    for (int it = 0; it < 2; it++) {
        int slot = it * 256 + tid;
        if (slot < 448) {
            int d = (slot * 9363) >> 17;     // /14
            int cu = slot - d * 14;
            lds[4480 + d * 116 + 98 + cu] = 0;
        }
    }
    __syncthreads();

    const int lane = tid & 63, wid = tid >> 6, quad = lane >> 4, l16 = lane & 15;
    // this lane's query (for S^T D-frag col and softmax)
    const int q = wid * 16 + l16;
    const int y = ty0 + (q >> 3), x = tx0 + (q & 7);
    const int token = base + y * 64 + x;
    const int sy = min(max(y - 3, 0), 57);
    const int sx = min(max(x - 3, 0), 57);
    const int ib = sy - ry0, jb = sx - rx0;
    const float* rp = rpb + head * 169 + (sy - y + 6) * 13 + (sx - x + 6);

    // Q as B-frag (bf16): B[k=dim][n=q]: lane reads dims quad*8..+8 of query q
    bf16x8 qf;
    {
        const float* qp = qb + (size_t)token * 128 + head * 32 + quad * 8;
        union { unsigned int u[4]; bf16x8 v; } pk;
#pragma unroll
        for (int e = 0; e < 4; e++) pk.u[e] = bfp2(qp[e * 2], qp[e * 2 + 1]);
        qf = pk.v;
    }

    // S^T: 14 m-tiles over 224 regions; A-frag = K rows
    f32x4 accS[14];
#pragma unroll
    for (int mt = 0; mt < 14; mt++) {
        bf16x8 kf = *(bf16x8*)&ldsu[(mt * 16 + l16) * 40 + quad * 8];
        accS[mt] = __builtin_amdgcn_mfma_f32_16x16x32_bf16(
            kf, qf, (f32x4){0.f, 0.f, 0.f, 0.f}, 0, 0, 0);
    }
    // mask + bias (region r = mt*16 + quad*4 + rg), in-place into accS
    float mx = -1e30f;
#pragma unroll
    for (int mt = 0; mt < 14; mt++) {
#pragma unroll
        for (int rg = 0; rg < 4; rg++) {
            int r = mt * 16 + quad * 4 + rg;
            int i = (r * 9363) >> 17;
            int j = r - i * 14;
            int di = i - ib, dj = j - jb;
            bool ok = ((unsigned)di < 7u) && ((unsigned)dj < 7u);
            float sv = ok ? (accS[mt][rg] + rp[di * 13 + dj]) : -1e30f;
            accS[mt][rg] = sv;
            mx = fmaxf(mx, sv);
        }
    }
    mx = fmaxf(mx, __shfl_xor(mx, 16));
    mx = fmaxf(mx, __shfl_xor(mx, 32));
    float sum = 0.f;
#pragma unroll
    for (int mt = 0; mt < 14; mt++)
#pragma unroll
        for (int rg = 0; rg < 4; rg++) {
            float e = __expf(accS[mt][rg] - mx);
            accS[mt][rg] = e;
            sum += e;
        }
    sum += __shfl_xor(sum, 16);
    sum += __shfl_xor(sum, 32);
    float inv = 1.f / sum;
    // P row q (normalized bf16): each frag's 4 regs = 4 consecutive regions
#pragma unroll
    for (int mt = 0; mt < 14; mt++) {
        uint2 pv;
        pv.x = bfp2(accS[mt][0] * inv, accS[mt][1] * inv);
        pv.y = bfp2(accS[mt][2] * inv, accS[mt][3] * inv);
        *(uint2*)&ldsu[16384 + q * 232 + mt * 16 + quad * 4] = pv;
    }
    __syncthreads();

    // PV: out = mfma(A=P rows of this wave's queries, B=Vt); 7 k-chunks x 2 d-tiles
    f32x4 o0 = (f32x4){0.f, 0.f, 0.f, 0.f};
    f32x4 o1 = (f32x4){0.f, 0.f, 0.f, 0.f};
#pragma unroll
    for (int kc = 0; kc < 7; kc++) {
        bf16x8 pa = *(bf16x8*)&ldsu[16384 + (wid * 16 + l16) * 232 + kc * 32 + quad * 8];
        bf16x8 v0 = *(bf16x8*)&ldsu[8960 + l16 * 232 + kc * 32 + quad * 8];
        bf16x8 v1 = *(bf16x8*)&ldsu[8960 + (16 + l16) * 232 + kc * 32 + quad * 8];
        o0 = __builtin_amdgcn_mfma_f32_16x16x32_bf16(pa, v0, o0, 0, 0, 0);
        o1 = __builtin_amdgcn_mfma_f32_16x16x32_bf16(pa, v1, o1, 0, 0, 0);
    }
    // out D: row = quad*4+rg (query within wave's 16), col = l16 (d) / +16
#pragma unroll
    for (int rg = 0; rg < 4; rg++) {
        int qo = wid * 16 + quad * 4 + rg;
        int toko = base + (ty0 + (qo >> 3)) * 64 + tx0 + (qo & 7);
        unsigned short* op = attnb + (size_t)toko * 128 + head * 32;
        op[l16] = bf1(o0[rg]);
        op[16 + l16] = bf1(o1[rg]);
    }
}

// ---------------- kpm4: proj+LN2+fc1+GELU+fc2+residuals; 8 waves / 32 tokens --------
__global__ __launch_bounds__(512) void kpm4(bfp16 attnb, fp x, bfp16 wt1, fp pb,
                                            fp g2, fp b2, bfp16 wt2, fp b1v,
                                            bfp16 wt3, fp b2v, float* __restrict__ out) {
    __shared__ unsigned int lds[12288];
    float* ldsf = (float*)lds;
    unsigned short* ldsu = (unsigned short*)lds;
    const int m0 = blockIdx.x * 32;
    const int tid = threadIdx.x;
    const int lane = tid & 63, wid = tid >> 6, quad = lane >> 4, l16 = lane & 15;

    {
        int m = tid >> 4, c16 = tid & 15;
        const uint4 v4 = *(const uint4*)(attnb + (size_t)(m0 + m) * CDIM + c16 * 8);
        *(uint4*)&lds[m * 64 + ((c16 ^ (m & 15)) << 2)] = v4;
    }
    __syncthreads();

    const int mt = wid & 1, nhf = wid >> 1;
    f32x4 pacc[2];
#pragma unroll
    for (int nt = 0; nt < 2; nt++) pacc[nt] = (f32x4){0.f, 0.f, 0.f, 0.f};
#pragma unroll
    for (int kk = 0; kk < 4; kk++) {
        int c = kk * 4 + quad;
        bf16x8 a = *(bf16x8*)&lds[(mt * 16 + l16) * 64 + ((c ^ l16) << 2)];
#pragma unroll
        for (int nt = 0; nt < 2; nt++) {
            int rt = nhf * 2 + nt;
            bf16x8 bf = *(const bf16x8*)(wt1 + (size_t)((rt * 4 + kk) * 64 + lane) * 8);
            pacc[nt] = __builtin_amdgcn_mfma_f32_16x16x32_bf16(a, bf, pacc[nt], 0, 0, 0);
        }
    }
    float sr[4] = {0.f, 0.f, 0.f, 0.f}, qr[4] = {0.f, 0.f, 0.f, 0.f};
#pragma unroll
    for (int nt = 0; nt < 2; nt++) {
        int col = nhf * 32 + nt * 16 + l16;
        float bias = pb[col];
#pragma unroll
        for (int r = 0; r < 4; r++) {
            int lrow = mt * 16 + quad * 4 + r;
            float hv = x[(size_t)(m0 + lrow) * CDIM + col] + pacc[nt][r] + bias;
            pacc[nt][r] = hv;
            sr[r] += hv; qr[r] += hv * hv;
        }
    }
#pragma unroll
    for (int mm = 1; mm <= 8; mm <<= 1) {
#pragma unroll
        for (int r = 0; r < 4; r++) {
            sr[r] += __shfl_xor(sr[r], mm);
            qr[r] += __shfl_xor(qr[r], mm);
        }
    }
    __syncthreads();
    if (l16 == 0) {
#pragma unroll
        for (int r = 0; r < 4; r++) {
            ldsf[wid * 32 + (quad * 4 + r) * 2]     = sr[r];
            ldsf[wid * 32 + (quad * 4 + r) * 2 + 1] = qr[r];
        }
    }
    __syncthreads();
    float mu[4], rs[4];
#pragma unroll
    for (int r = 0; r < 4; r++) {
        float st = 0.f, qt = 0.f;
#pragma unroll
        for (int p = 0; p < 4; p++) {
            int w2 = p * 2 + mt;
            st += ldsf[w2 * 32 + (quad * 4 + r) * 2];
            qt += ldsf[w2 * 32 + (quad * 4 + r) * 2 + 1];
        }
        mu[r] = st * (1.f / 128.f);
        rs[r] = rsqrtf(qt * (1.f / 128.f) - mu[r] * mu[r] + LEPS);
    }
#pragma unroll
    for (int nt = 0; nt < 2; nt++) {
        int col = nhf * 32 + nt * 16 + l16;
        float gg = g2[col], bbv = b2[col];
        int c16h = col >> 3, cw = col & 7;
#pragma unroll
        for (int r = 0; r < 4; r++) {
            int lrow = mt * 16 + quad * 4 + r;
            ldsu[4096 + lrow * 128 + ((c16h ^ (lrow & 15)) << 3) + cw] =
                bf1((pacc[nt][r] - mu[r]) * rs[r] * gg + bbv);
        }
    }
    __syncthreads();

#pragma unroll
    for (int ht = 0; ht < 4; ht++) {
        f32x4 acc0 = (f32x4){0.f, 0.f, 0.f, 0.f};
        f32x4 acc1 = (f32x4){0.f, 0.f, 0.f, 0.f};
#pragma unroll
        for (int kk = 0; kk < 4; kk++) {
            int c = kk * 4 + quad;
            bf16x8 wf = *(const bf16x8*)(wt2 + (size_t)(((wid * 4 + ht) * 4 + kk) * 64 + lane) * 8);
            bf16x8 x0 = *(bf16x8*)&lds[2048 + l16 * 64 + ((c ^ l16) << 2)];
            bf16x8 x1 = *(bf16x8*)&lds[2048 + (16 + l16) * 64 + ((c ^ l16) << 2)];
            acc0 = __builtin_amdgcn_mfma_f32_16x16x32_bf16(wf, x0, acc0, 0, 0, 0);
            acc1 = __builtin_amdgcn_mfma_f32_16x16x32_bf16(wf, x1, acc1, 0, 0, 0);
        }
        const int hidb = wid * 64 + ht * 16 + quad * 4;
        const float4 bb = *(const float4*)(b1v + hidb);
        const int c16y = hidb >> 3;
        const int woff = (quad & 1) << 1;
#pragma unroll
        for (int t = 0; t < 2; t++) {
            f32x4 a = t ? acc1 : acc0;
            int row = t * 16 + l16;
            float z0 = a[0] + bb.x, z1 = a[1] + bb.y, z2 = a[2] + bb.z, z3 = a[3] + bb.w;
            float g0 = 0.5f * z0 * (1.f + erff(z0 * 0.70710678118654752f));
            float g1 = 0.5f * z1 * (1.f + erff(z1 * 0.70710678118654752f));
            float g2v = 0.5f * z2 * (1.f + erff(z2 * 0.70710678118654752f));
            float g3 = 0.5f * z3 * (1.f + erff(z3 * 0.70710678118654752f));
            uint2 val; val.x = bfp2(g0, g1); val.y = bfp2(g2v, g3);
            *(uint2*)&lds[4096 + row * 256 + ((c16y ^ (row & 15)) << 2) + woff] = val;
        }
    }
    __syncthreads();

    f32x4 facc[2];
#pragma unroll
    for (int nt = 0; nt < 2; nt++) facc[nt] = (f32x4){0.f, 0.f, 0.f, 0.f};
#pragma unroll
    for (int kc = 0; kc < 16; kc++) {
        int c = kc * 4 + quad;
        bf16x8 a = *(bf16x8*)&lds[4096 + (mt * 16 + l16) * 256 + ((c ^ l16) << 2)];
#pragma unroll
        for (int nt = 0; nt < 2; nt++) {
            int rt = nhf * 2 + nt;
            bf16x8 bf = *(const bf16x8*)(wt3 + (size_t)((rt * 16 + kc) * 64 + lane) * 8);
            facc[nt] = __builtin_amdgcn_mfma_f32_16x16x32_bf16(a, bf, facc[nt], 0, 0, 0);
        }
    }
#pragma unroll
    for (int nt = 0; nt < 2; nt++) {
        int col = nhf * 32 + nt * 16 + l16;
        float bias = b2v[col];
#pragma unroll
        for (int r = 0; r < 4; r++) {
            int lrow = mt * 16 + quad * 4 + r;
            out[(size_t)(m0 + lrow) * CDIM + col] = pacc[nt][r] + facc[nt][r] + bias;
        }
    }
}

extern "C" void kernel_launch(void* const* d_in, const int* in_sizes, int n_in,
                              void* d_out, int out_size, void* d_ws, size_t ws_size,
                              hipStream_t stream) {
    fp x      = (fp)d_in[0];
    fp ln1_g  = (fp)d_in[1];
    fp ln1_b  = (fp)d_in[2];
    fp qkv_w  = (fp)d_in[3];
    fp qkv_b  = (fp)d_in[4];
    fp rpb    = (fp)d_in[5];
    fp proj_w = (fp)d_in[6];
    fp proj_b = (fp)d_in[7];
    fp ln2_g  = (fp)d_in[8];
    fp ln2_b  = (fp)d_in[9];
    fp fc1_w  = (fp)d_in[10];
    fp fc1_b  = (fp)d_in[11];
    fp fc2_w  = (fp)d_in[12];
    fp fc2_b  = (fp)d_in[13];
    float* out = (float*)d_out;

    float* ws = (float*)d_ws;
    float* h  = ws;                                                    // (spare)
    unsigned short* xn = (unsigned short*)(h + (size_t)TOKS * CDIM);   // (spare)
    unsigned short* hn = xn + (size_t)TOKS * CDIM;                     // (spare)
    float* qb = (float*)(hn + (size_t)TOKS * CDIM);
    unsigned short* kvb   = (unsigned short*)(qb + (size_t)TOKS * CDIM);
    unsigned short* attnb = kvb + (size_t)TOKS * 256;
    unsigned short* wt    = attnb + (size_t)TOKS * CDIM;

    unsigned short* wt0 = wt;            // qkv  [384][128]
    unsigned short* wt1 = wt + 49152;    // proj frag-major
    unsigned short* wt2 = wt + 65536;    // fc1  frag-major
    unsigned short* wt3 = wt + 131072;   // fc2  frag-major

    prep<<<768, 256, 0, stream>>>(qkv_w, proj_w, fc1_w, fc2_w, wt);
    k1_mfma<<<dim3(TOKS / 128, 6), 256, 0, stream>>>(x, ln1_g, ln1_b, wt0, qkv_b, qb, kvb);
    k2_attn<<<TOKS / 64 * NH, 256, 0, stream>>>(qb, kvb, rpb, attnb);
    kpm4<<<TOKS / 32, 512, 0, stream>>>(attnb, x, wt1, proj_b, ln2_g, ln2_b,
                                        wt2, fc1_b, wt3, fc2_b, out);
}

// Round 16
// 129.840 us; speedup vs baseline: 1.0288x; 1.0288x over previous
//
#include <hip/hip_runtime.h>
#include <math.h>

#define TOKS 16384
#define CDIM 128
#define NH 4
#define HD 32
#define HID 512
#define QSCALE 0.17677669529663687f
#define LEPS 1e-5f

typedef const float* fp;
typedef const unsigned short* bfp16;
typedef __attribute__((ext_vector_type(8))) short bf16x8;
typedef __attribute__((ext_vector_type(4))) float f32x4;

__device__ inline unsigned int bfp2(float a, float b) {
    unsigned int ua = __float_as_uint(a); ua = (ua + 0x7FFFu + ((ua >> 16) & 1u)) >> 16;
    unsigned int ub = __float_as_uint(b); ub = (ub + 0x7FFFu + ((ub >> 16) & 1u)) >> 16;
    return ua | (ub << 16);
}
__device__ inline unsigned short bf1(float a) {
    unsigned int u = __float_as_uint(a);
    return (unsigned short)((u + 0x7FFFu + ((u >> 16) & 1u)) >> 16);
}
__device__ inline float lo16(unsigned int u) { return __uint_as_float(u << 16); }
__device__ inline float hi16(unsigned int u) { return __uint_as_float(u & 0xFFFF0000u); }

// ---------------- k1: fused LN1(x) + QKV GEMM; wt0 converted INLINE from f32 --------
// Blocks 0..767: compute (m0 = (blk&127)*128, nb = (blk>>7)*64). B-staging reads the
// qkv_w f32 slice directly (coalesced 8-wide rows, L2-resident) and packs bf16 into
// the same swizzled LDS layout (bit-identical to prep's conversion).
// Blocks 768..1343: fragment-major conversion of proj/fc1/fc2 weights (consumed by
// kpm4 two dispatches later).
__global__ __launch_bounds__(256) void k1_mfma(fp x, fp g1, fp b1, fp qw, fp wb,
                                               fp pw, fp f1w, fp f2w,
                                               unsigned short* __restrict__ wt,
                                               float* __restrict__ qb,
                                               unsigned short* __restrict__ kvb) {
    const int blk = blockIdx.x;
    const int tid = threadIdx.x;
    if (blk >= 768) {   // ---- prep tail: wt1/wt2/wt3 frag-major ----
        int e = 49152 + (blk - 768) * 256 + tid;
        float v;
        if (e < 65536) {             // wt1f: proj W[128 out][128 k], frags (rt*4+kk)
            int i = e - 49152;
            int frag = i >> 9, w = i & 511, lane = w >> 3, el = w & 7;
            int rt = frag >> 2, kk = frag & 3;
            int row = rt * 16 + (lane & 15);
            int k = kk * 32 + (lane >> 4) * 8 + el;
            v = pw[(size_t)k * 128 + row];
        } else if (e < 131072) {     // wt2f: fc1 W[512 hid][128 k]
            int i = e - 65536;
            int frag = i >> 9, w = i & 511, lane = w >> 3, el = w & 7;
            int rt = frag >> 2, kk = frag & 3;
            int row = rt * 16 + (lane & 15);
            int k = kk * 32 + (lane >> 4) * 8 + el;
            v = f1w[(size_t)k * 512 + row];
        } else {                     // wt3f: fc2 W[128 out][512 k], frags (rt*16+kc)
            int i = e - 131072;
            int frag = i >> 9, w = i & 511, lane = w >> 3, el = w & 7;
            int rt = frag >> 4, kc = frag & 15;
            int row = rt * 16 + (lane & 15);
            int k = kc * 32 + (lane >> 4) * 8 + el;
            v = f2w[(size_t)k * 128 + row];
        }
        wt[e] = bf1(v);
        return;
    }

    __shared__ unsigned int lds[12288];
    const int m0 = (blk & 127) << 7;
    const int nb = (blk >> 7) * 64;
    // ---- A-staging with fused LN1 ----
#pragma unroll
    for (int i = 0; i < 8; i++) {
        int slot = tid + i * 256;
        int m = slot >> 4, c16 = slot & 15;
        const float4 v0 = *(const float4*)(x + (size_t)(m0 + m) * CDIM + c16 * 8);
        const float4 v1 = *(const float4*)(x + (size_t)(m0 + m) * CDIM + c16 * 8 + 4);
        float s = v0.x + v0.y + v0.z + v0.w + v1.x + v1.y + v1.z + v1.w;
        float q = v0.x * v0.x + v0.y * v0.y + v0.z * v0.z + v0.w * v0.w
                + v1.x * v1.x + v1.y * v1.y + v1.z * v1.z + v1.w * v1.w;
#pragma unroll
        for (int mm = 8; mm >= 1; mm >>= 1) { s += __shfl_xor(s, mm); q += __shfl_xor(q, mm); }
        float mu = s * (1.f / 128.f);
        float rs = rsqrtf(q * (1.f / 128.f) - mu * mu + LEPS);
        const float4 ga = *(const float4*)(g1 + c16 * 8);
        const float4 gb = *(const float4*)(g1 + c16 * 8 + 4);
        const float4 ba = *(const float4*)(b1 + c16 * 8);
        const float4 bb = *(const float4*)(b1 + c16 * 8 + 4);
        uint4 o;
        o.x = bfp2((v0.x - mu) * rs * ga.x + ba.x, (v0.y - mu) * rs * ga.y + ba.y);
        o.y = bfp2((v0.z - mu) * rs * ga.z + ba.z, (v0.w - mu) * rs * ga.w + ba.w);
        o.z = bfp2((v1.x - mu) * rs * gb.x + bb.x, (v1.y - mu) * rs * gb.y + bb.y);
        o.w = bfp2((v1.z - mu) * rs * gb.z + bb.z, (v1.w - mu) * rs * gb.w + bb.w);
        *(uint4*)&lds[m * 64 + ((c16 ^ (m & 15)) << 2)] = o;
    }
    // ---- B-staging: convert qkv_w f32 slice -> bf16 swizzled LDS (same layout) ----
    {
        const int k4 = tid >> 3;       // k rows k4*4 .. +4  (0..127)
        const int no = tid & 7;        // n octet: n = no*8 + j
        float rw[4][8];
#pragma unroll
        for (int e4 = 0; e4 < 4; e4++) {
            const float* src = qw + (size_t)(k4 * 4 + e4) * 384 + nb + no * 8;
            *(float4*)&rw[e4][0] = *(const float4*)src;
            *(float4*)&rw[e4][4] = *(const float4*)(src + 4);
        }
        const int c16 = k4 >> 1, half = k4 & 1;
#pragma unroll
        for (int j = 0; j < 8; j++) {
            int n = no * 8 + j;
            uint2 pk;
            pk.x = bfp2(rw[0][j], rw[1][j]);
            pk.y = bfp2(rw[2][j], rw[3][j]);
            *(uint2*)&lds[8192 + n * 64 + ((c16 ^ (n & 15)) << 2) + half * 2] = pk;
        }
    }
    __syncthreads();

    const int lane = tid & 63, wid = tid >> 6, quad = lane >> 4, l16 = lane & 15;
    f32x4 acc[2][4];
#pragma unroll
    for (int mt = 0; mt < 2; mt++)
#pragma unroll
        for (int nt = 0; nt < 4; nt++) acc[mt][nt] = (f32x4){0.f, 0.f, 0.f, 0.f};
#pragma unroll
    for (int kk = 0; kk < 4; kk++) {
        int c = kk * 4 + quad;
        bf16x8 a0 = *(bf16x8*)&lds[(wid * 32 + l16) * 64 + (c ^ l16) * 4];
        bf16x8 a1 = *(bf16x8*)&lds[(wid * 32 + 16 + l16) * 64 + (c ^ l16) * 4];
#pragma unroll
        for (int nt = 0; nt < 4; nt++) {
            bf16x8 bf = *(bf16x8*)&lds[8192 + (nt * 16 + l16) * 64 + (c ^ l16) * 4];
            acc[0][nt] = __builtin_amdgcn_mfma_f32_16x16x32_bf16(a0, bf, acc[0][nt], 0, 0, 0);
            acc[1][nt] = __builtin_amdgcn_mfma_f32_16x16x32_bf16(a1, bf, acc[1][nt], 0, 0, 0);
        }
    }
#pragma unroll
    for (int nt = 0; nt < 4; nt++) {
        int col = nb + nt * 16 + l16;
        float bias = wb[col];
#pragma unroll
        for (int mt = 0; mt < 2; mt++)
#pragma unroll
            for (int r = 0; r < 4; r++) {
                int row = m0 + wid * 32 + mt * 16 + quad * 4 + r;
                float vres = acc[mt][nt][r] + bias;
                if (col < 128)
                    qb[(size_t)row * 128 + col] = vres * QSCALE;
                else if (col < 256)
                    kvb[(size_t)row * 256 + (col - 128)] = bf1(vres);
                else
                    kvb[(size_t)row * 256 + 128 + (col - 256)] = bf1(vres);
            }
    }
}

// ---------------- k2: tiled neighborhood attention (R6/R12-verified version) ----------
__global__ __launch_bounds__(512) void k2_attn(const float* __restrict__ qb,
                                               const unsigned short* __restrict__ kvb,
                                               fp rpb, unsigned short* __restrict__ attnb) {
    __shared__ unsigned int lds[25088];          // 196 rows x 128 uints (K 64 | V 64)
    const int tile = blockIdx.x;                 // 256 tiles
    const int bb = tile >> 6;
    const int ty0 = ((tile >> 3) & 7) << 3;
    const int tx0 = (tile & 7) << 3;
    const int ry0 = min(max(ty0 - 3, 0), 50);
    const int rx0 = min(max(tx0 - 3, 0), 50);
    const int tid = threadIdx.x;

#pragma unroll
    for (int it = 0; it < 13; it++) {
        int slot = it * 512 + tid;
        if (slot < 6272) {
            int r = slot >> 5, c = slot & 31;
            int i = r / 14, j = r - i * 14;
            const uint4 v = *(const uint4*)(kvb + (size_t)((bb << 12) + (ry0 + i) * 64 + rx0 + j) * 256 + c * 8);
            *(uint4*)&lds[r * 128 + ((c ^ (r & 7)) << 2)] = v;
        }
    }

    const int dh = tid & 1;
    const int head = (tid >> 1) & 3;
    const int t = tid >> 3;
    const int tx = t & 7, ty = t >> 3;
    const int y = ty0 + ty, x = tx0 + tx;
    const int token = (bb << 12) + y * 64 + x;
    const int sy = min(max(y - 3, 0), 57);
    const int sx = min(max(x - 3, 0), 57);
    const int ib = sy - ry0, jb = sx - rx0;
    const float* rp = rpb + head * 169 + (sy - y + 6) * 13 + (sx - x + 6);

    float q[16];
    {
        const float4* qp = (const float4*)(qb + (size_t)token * 128 + head * 32 + dh * 16);
        float4 a = qp[0], b = qp[1], c = qp[2], d = qp[3];
        q[0] = a.x; q[1] = a.y; q[2] = a.z; q[3] = a.w;
        q[4] = b.x; q[5] = b.y; q[6] = b.z; q[7] = b.w;
        q[8] = c.x; q[9] = c.y; q[10] = c.z; q[11] = c.w;
        q[12] = d.x; q[13] = d.y; q[14] = d.z; q[15] = d.w;
    }
    __syncthreads();

    const int cb = (head << 2) + (dh << 1);
    float m = -1e30f, l = 0.f;
    float o[16];
#pragma unroll
    for (int i2 = 0; i2 < 16; i2++) o[i2] = 0.f;

    for (int dy = 0; dy < 7; dy++) {
        float s[7];
#pragma unroll
        for (int dx = 0; dx < 7; dx++) {
            int r = (ib + dy) * 14 + jb + dx;
            int sw = r & 7;
            const uint4 k0 = *(const uint4*)&lds[r * 128 + ((cb ^ sw) << 2)];
            const uint4 k1 = *(const uint4*)&lds[r * 128 + (((cb + 1) ^ sw) << 2)];
            float ss = q[0] * lo16(k0.x) + q[1] * hi16(k0.x)
                     + q[2] * lo16(k0.y) + q[3] * hi16(k0.y)
                     + q[4] * lo16(k0.z) + q[5] * hi16(k0.z)
                     + q[6] * lo16(k0.w) + q[7] * hi16(k0.w)
                     + q[8] * lo16(k1.x) + q[9] * hi16(k1.x)
                     + q[10] * lo16(k1.y) + q[11] * hi16(k1.y)
                     + q[12] * lo16(k1.z) + q[13] * hi16(k1.z)
                     + q[14] * lo16(k1.w) + q[15] * hi16(k1.w);
            ss += __shfl_xor(ss, 1);
            s[dx] = ss + rp[dy * 13 + dx];
        }
        float rm = s[0];
#pragma unroll
        for (int dx = 1; dx < 7; dx++) rm = fmaxf(rm, s[dx]);
        float mn = fmaxf(m, rm);
        float cf = __expf(m - mn);
        l *= cf;
#pragma unroll
        for (int i2 = 0; i2 < 16; i2++) o[i2] *= cf;
#pragma unroll
        for (int dx = 0; dx < 7; dx++) {
            int r = (ib + dy) * 14 + jb + dx;
            int sw = r & 7;
            const uint4 v0 = *(const uint4*)&lds[r * 128 + (((cb + 16) ^ sw) << 2)];
            const uint4 v1 = *(const uint4*)&lds[r * 128 + (((cb + 17) ^ sw) << 2)];
            float p = __expf(s[dx] - mn);
            l += p;
            o[0] += p * lo16(v0.x); o[1] += p * hi16(v0.x);
            o[2] += p * lo16(v0.y); o[3] += p * hi16(v0.y);
            o[4] += p * lo16(v0.z); o[5] += p * hi16(v0.z);
            o[6] += p * lo16(v0.w); o[7] += p * hi16(v0.w);
            o[8] += p * lo16(v1.x); o[9] += p * hi16(v1.x);
            o[10] += p * lo16(v1.y); o[11] += p * hi16(v1.y);
            o[12] += p * lo16(v1.z); o[13] += p * hi16(v1.z);
            o[14] += p * lo16(v1.w); o[15] += p * hi16(v1.w);
        }
        m = mn;
    }
    float inv = 1.f / l;
    unsigned short* op = attnb + (size_t)token * 128 + head * 32 + dh * 16;
    uint4 ov;
    ov.x = bfp2(o[0] * inv, o[1] * inv); ov.y = bfp2(o[2] * inv, o[3] * inv);
    ov.z = bfp2(o[4] * inv, o[5] * inv); ov.w = bfp2(o[6] * inv, o[7] * inv);
    *(uint4*)op = ov;
    ov.x = bfp2(o[8] * inv, o[9] * inv); ov.y = bfp2(o[10] * inv, o[11] * inv);
    ov.z = bfp2(o[12] * inv, o[13] * inv); ov.w = bfp2(o[14] * inv, o[15] * inv);
    *(uint4*)(op + 8) = ov;
}

// ---------------- kpm4: proj+LN2+fc1+GELU+fc2+residuals; 8 waves / 32 tokens --------
__global__ __launch_bounds__(512) void kpm4(bfp16 attnb, fp x, bfp16 wt1, fp pb,
                                            fp g2, fp b2, bfp16 wt2, fp b1v,
                                            bfp16 wt3, fp b2v, float* __restrict__ out) {
    __shared__ unsigned int lds[12288];
    float* ldsf = (float*)lds;
    unsigned short* ldsu = (unsigned short*)lds;
    const int m0 = blockIdx.x * 32;
    const int tid = threadIdx.x;
    const int lane = tid & 63, wid = tid >> 6, quad = lane >> 4, l16 = lane & 15;

    {
        int m = tid >> 4, c16 = tid & 15;
        const uint4 v4 = *(const uint4*)(attnb + (size_t)(m0 + m) * CDIM + c16 * 8);
        *(uint4*)&lds[m * 64 + ((c16 ^ (m & 15)) << 2)] = v4;
    }
    __syncthreads();

    const int mt = wid & 1, nhf = wid >> 1;
    f32x4 pacc[2];
#pragma unroll
    for (int nt = 0; nt < 2; nt++) pacc[nt] = (f32x4){0.f, 0.f, 0.f, 0.f};
#pragma unroll
    for (int kk = 0; kk < 4; kk++) {
        int c = kk * 4 + quad;
        bf16x8 a = *(bf16x8*)&lds[(mt * 16 + l16) * 64 + ((c ^ l16) << 2)];
#pragma unroll
        for (int nt = 0; nt < 2; nt++) {
            int rt = nhf * 2 + nt;
            bf16x8 bf = *(const bf16x8*)(wt1 + (size_t)((rt * 4 + kk) * 64 + lane) * 8);
            pacc[nt] = __builtin_amdgcn_mfma_f32_16x16x32_bf16(a, bf, pacc[nt], 0, 0, 0);
        }
    }
    float sr[4] = {0.f, 0.f, 0.f, 0.f}, qr[4] = {0.f, 0.f, 0.f, 0.f};
#pragma unroll
    for (int nt = 0; nt < 2; nt++) {
        int col = nhf * 32 + nt * 16 + l16;
        float bias = pb[col];
#pragma unroll
        for (int r = 0; r < 4; r++) {
            int lrow = mt * 16 + quad * 4 + r;
            float hv = x[(size_t)(m0 + lrow) * CDIM + col] + pacc[nt][r] + bias;
            pacc[nt][r] = hv;
            sr[r] += hv; qr[r] += hv * hv;
        }
    }
#pragma unroll
    for (int mm = 1; mm <= 8; mm <<= 1) {
#pragma unroll
        for (int r = 0; r < 4; r++) {
            sr[r] += __shfl_xor(sr[r], mm);
            qr[r] += __shfl_xor(qr[r], mm);
        }
    }
    __syncthreads();
    if (l16 == 0) {
#pragma unroll
        for (int r = 0; r < 4; r++) {
            ldsf[wid * 32 + (quad * 4 + r) * 2]     = sr[r];
            ldsf[wid * 32 + (quad * 4 + r) * 2 + 1] = qr[r];
        }
    }
    __syncthreads();
    float mu[4], rs[4];
#pragma unroll
    for (int r = 0; r < 4; r++) {
        float st = 0.f, qt = 0.f;
#pragma unroll
        for (int p = 0; p < 4; p++) {
            int w2 = p * 2 + mt;
            st += ldsf[w2 * 32 + (quad * 4 + r) * 2];
            qt += ldsf[w2 * 32 + (quad * 4 + r) * 2 + 1];
        }
        mu[r] = st * (1.f / 128.f);
        rs[r] = rsqrtf(qt * (1.f / 128.f) - mu[r] * mu[r] + LEPS);
    }
#pragma unroll
    for (int nt = 0; nt < 2; nt++) {
        int col = nhf * 32 + nt * 16 + l16;
        float gg = g2[col], bbv = b2[col];
        int c16h = col >> 3, cw = col & 7;
#pragma unroll
        for (int r = 0; r < 4; r++) {
            int lrow = mt * 16 + quad * 4 + r;
            ldsu[4096 + lrow * 128 + ((c16h ^ (lrow & 15)) << 3) + cw] =
                bf1((pacc[nt][r] - mu[r]) * rs[r] * gg + bbv);
        }
    }
    __syncthreads();

#pragma unroll
    for (int ht = 0; ht < 4; ht++) {
        f32x4 acc0 = (f32x4){0.f, 0.f, 0.f, 0.f};
        f32x4 acc1 = (f32x4){0.f, 0.f, 0.f, 0.f};
#pragma unroll
        for (int kk = 0; kk < 4; kk++) {
            int c = kk * 4 + quad;
            bf16x8 wf = *(const bf16x8*)(wt2 + (size_t)(((wid * 4 + ht) * 4 + kk) * 64 + lane) * 8);
            bf16x8 x0 = *(bf16x8*)&lds[2048 + l16 * 64 + ((c ^ l16) << 2)];
            bf16x8 x1 = *(bf16x8*)&lds[2048 + (16 + l16) * 64 + ((c ^ l16) << 2)];
            acc0 = __builtin_amdgcn_mfma_f32_16x16x32_bf16(wf, x0, acc0, 0, 0, 0);
            acc1 = __builtin_amdgcn_mfma_f32_16x16x32_bf16(wf, x1, acc1, 0, 0, 0);
        }
        const int hidb = wid * 64 + ht * 16 + quad * 4;
        const float4 bb = *(const float4*)(b1v + hidb);
        const int c16y = hidb >> 3;
        const int woff = (quad & 1) << 1;
#pragma unroll
        for (int t = 0; t < 2; t++) {
            f32x4 a = t ? acc1 : acc0;
            int row = t * 16 + l16;
            float z0 = a[0] + bb.x, z1 = a[1] + bb.y, z2 = a[2] + bb.z, z3 = a[3] + bb.w;
            float g0 = 0.5f * z0 * (1.f + erff(z0 * 0.70710678118654752f));
            float g1 = 0.5f * z1 * (1.f + erff(z1 * 0.70710678118654752f));
            float g2v = 0.5f * z2 * (1.f + erff(z2 * 0.70710678118654752f));
            float g3 = 0.5f * z3 * (1.f + erff(z3 * 0.70710678118654752f));
            uint2 val; val.x = bfp2(g0, g1); val.y = bfp2(g2v, g3);
            *(uint2*)&lds[4096 + row * 256 + ((c16y ^ (row & 15)) << 2) + woff] = val;
        }
    }
    __syncthreads();

    f32x4 facc[2];
#pragma unroll
    for (int nt = 0; nt < 2; nt++) facc[nt] = (f32x4){0.f, 0.f, 0.f, 0.f};
#pragma unroll
    for (int kc = 0; kc < 16; kc++) {
        int c = kc * 4 + quad;
        bf16x8 a = *(bf16x8*)&lds[4096 + (mt * 16 + l16) * 256 + ((c ^ l16) << 2)];
#pragma unroll
        for (int nt = 0; nt < 2; nt++) {
            int rt = nhf * 2 + nt;
            bf16x8 bf = *(const bf16x8*)(wt3 + (size_t)((rt * 16 + kc) * 64 + lane) * 8);
            facc[nt] = __builtin_amdgcn_mfma_f32_16x16x32_bf16(a, bf, facc[nt], 0, 0, 0);
        }
    }
#pragma unroll
    for (int nt = 0; nt < 2; nt++) {
        int col = nhf * 32 + nt * 16 + l16;
        float bias = b2v[col];
#pragma unroll
        for (int r = 0; r < 4; r++) {
            int lrow = mt * 16 + quad * 4 + r;
            out[(size_t)(m0 + lrow) * CDIM + col] = pacc[nt][r] + facc[nt][r] + bias;
        }
    }
}

extern "C" void kernel_launch(void* const* d_in, const int* in_sizes, int n_in,
                              void* d_out, int out_size, void* d_ws, size_t ws_size,
                              hipStream_t stream) {
    fp x      = (fp)d_in[0];
    fp ln1_g  = (fp)d_in[1];
    fp ln1_b  = (fp)d_in[2];
    fp qkv_w  = (fp)d_in[3];
    fp qkv_b  = (fp)d_in[4];
    fp rpb    = (fp)d_in[5];
    fp proj_w = (fp)d_in[6];
    fp proj_b = (fp)d_in[7];
    fp ln2_g  = (fp)d_in[8];
    fp ln2_b  = (fp)d_in[9];
    fp fc1_w  = (fp)d_in[10];
    fp fc1_b  = (fp)d_in[11];
    fp fc2_w  = (fp)d_in[12];
    fp fc2_b  = (fp)d_in[13];
    float* out = (float*)d_out;

    float* ws = (float*)d_ws;
    float* h  = ws;                                                    // (spare)
    unsigned short* xn = (unsigned short*)(h + (size_t)TOKS * CDIM);   // (spare)
    unsigned short* hn = xn + (size_t)TOKS * CDIM;                     // (spare)
    float* qb = (float*)(hn + (size_t)TOKS * CDIM);
    unsigned short* kvb   = (unsigned short*)(qb + (size_t)TOKS * CDIM);
    unsigned short* attnb = kvb + (size_t)TOKS * 256;
    unsigned short* wt    = attnb + (size_t)TOKS * CDIM;

    unsigned short* wt1 = wt + 49152;    // proj frag-major
    unsigned short* wt2 = wt + 65536;    // fc1  frag-major
    unsigned short* wt3 = wt + 131072;   // fc2  frag-major

    k1_mfma<<<768 + 576, 256, 0, stream>>>(x, ln1_g, ln1_b, qkv_w, qkv_b,
                                           proj_w, fc1_w, fc2_w, wt, qb, kvb);
    k2_attn<<<TOKS / 64, 512, 0, stream>>>(qb, kvb, rpb, attnb);
    kpm4<<<TOKS / 32, 512, 0, stream>>>(attnb, x, wt1, proj_b, ln2_g, ln2_b,
                                        wt2, fc1_b, wt3, fc2_b, out);
}